// Round 1
// baseline (1902.033 us; speedup 1.0000x reference)
//
#include <hip/hip_runtime.h>
#include <hip/hip_bf16.h>

typedef __attribute__((ext_vector_type(8))) short bf16x8;
typedef __attribute__((ext_vector_type(4))) float f32x4;

#define EPSV 1e-5f

#define NN 50000
#define NE 800000
#define NG 64

__device__ __forceinline__ unsigned short f2bf(float f) {
  union { float f; unsigned u; } v; v.f = f;
  unsigned r = v.u + 0x7FFFu + ((v.u >> 16) & 1u);
  return (unsigned short)(r >> 16);
}

// ---------------- conversion kernels ----------------

// x [50000*128] and e [800000*32] f32 -> bf16, vectorized
__global__ __launch_bounds__(256) void cvt_vec_kernel(
    const float* __restrict__ x, const float* __restrict__ e,
    unsigned short* __restrict__ xb, unsigned short* __restrict__ eb) {
  const int NX4 = (NN * 128) / 4;     // 1,600,000
  const int NE4 = (NE * 32) / 4;      // 6,400,000
  const int total = NX4 + NE4;
  for (int idx = blockIdx.x * 256 + threadIdx.x; idx < total;
       idx += gridDim.x * 256) {
    float4 v = (idx < NX4) ? ((const float4*)x)[idx]
                           : ((const float4*)e)[idx - NX4];
    ushort4 o;
    o.x = f2bf(v.x); o.y = f2bf(v.y); o.z = f2bf(v.z); o.w = f2bf(v.w);
    if (idx < NX4) ((ushort4*)xb)[idx] = o;
    else           ((ushort4*)eb)[idx - NX4] = o;
  }
}

// u + weight transposes (tiny)
__global__ __launch_bounds__(256) void cvt_small_kernel(
    const float* __restrict__ u,
    const float* __restrict__ eW1, const float* __restrict__ eW2,
    const float* __restrict__ nW1, const float* __restrict__ nW2,
    unsigned short* __restrict__ ub,
    unsigned short* __restrict__ eW1T, unsigned short* __restrict__ eW2T,
    unsigned short* __restrict__ nW1T, unsigned short* __restrict__ nW2T) {
  int i = blockIdx.x * 256 + threadIdx.x;
  const int R0 = NG * 32;          // 2048 : ub
  const int R1 = R0 + 128 * 320;   // eW1T  (K=320)
  const int R2 = R1 + 128 * 128;   // eW2T
  const int R3 = R2 + 128 * 320;   // nW1T  (K padded 288->320)
  const int R4 = R3 + 128 * 128;   // nW2T
  if (i < R0) {
    ub[i] = f2bf(u[i]);
  } else if (i < R1) {
    int j = i - R0; int n = j / 320, k = j % 320;
    eW1T[j] = f2bf(eW1[k * 128 + n]);
  } else if (i < R2) {
    int j = i - R1; int n = j / 128, k = j % 128;
    eW2T[j] = f2bf(eW2[k * 128 + n]);
  } else if (i < R3) {
    int j = i - R2; int n = j / 320, k = j % 320;
    nW1T[j] = (k < 288) ? f2bf(nW1[k * 128 + n]) : (unsigned short)0;
  } else if (i < R4) {
    int j = i - R3; int n = j / 128, k = j % 128;
    nW2T[j] = f2bf(nW2[k * 128 + n]);
  }
}

// ---------------- fused MLP kernel (edge MODE=0 / node MODE=1) ----------------
// 128 rows per block, 512 threads = 8 waves; wave w owns rows w*16..w*16+15
// (all 128 output cols), so LayerNorm reduces purely via shfl within the wave.
template <int MODE>
__global__ __launch_bounds__(512, 1) void mlp_kernel(
    const unsigned short* __restrict__ ebuf,  // MODE0: eb [NE][32]
    const unsigned short* __restrict__ xb,    // [NN][128]
    const unsigned short* __restrict__ ub,    // [NG][32]
    const float* __restrict__ aggin,          // MODE1: e2n [NN][128] f32
    const int* __restrict__ rowIdx, const int* __restrict__ colIdx,
    const int* __restrict__ batch,
    const unsigned short* __restrict__ W1T,   // [128][320] bf16
    const unsigned short* __restrict__ W2T,   // [128][128] bf16
    const float* __restrict__ b1, const float* __restrict__ b2,
    const float* __restrict__ gam, const float* __restrict__ bet,
    float* __restrict__ out, float* __restrict__ aggout, int nRows) {
  __shared__ unsigned short Asm[128][328];  // A tile, K padded to 320 (+8 pad)
  __shared__ unsigned short Bsm[128][72];   // weight K-chunk [N][64] (+8 pad)
  __shared__ unsigned short Hsm[128][136];  // h1 bf16 [M][128] (+8 pad)
  __shared__ float cb1[128], cb2[128], cg[128], cbt[128];

  const int tid = threadIdx.x;
  if (tid < 128) {
    cb1[tid] = b1[tid]; cb2[tid] = b2[tid];
    cg[tid] = gam[tid]; cbt[tid] = bet[tid];
  }

  // ---- stage A tile: 4 threads per row ----
  {
    const int r = tid >> 2, q = tid & 3;
    const int grow = blockIdx.x * 128 + r;
    if (MODE == 0) {
      const int rcv = colIdx[grow];
      const int snd = rowIdx[grow];
      const int g = batch[snd];
      const uint4* esrc = (const uint4*)(ebuf + (size_t)grow * 32);
      const uint4* xr = (const uint4*)(xb + (size_t)rcv * 128);
      const uint4* xs = (const uint4*)(xb + (size_t)snd * 128);
      const uint4* us = (const uint4*)(ub + g * 32);
#pragma unroll
      for (int c = 0; c < 10; ++c) {
        const int cc = q * 10 + c;
        uint4 v;
        if (cc < 4)       v = esrc[cc];
        else if (cc < 20) v = xr[cc - 4];
        else if (cc < 36) v = xs[cc - 20];
        else              v = us[cc - 36];
        *(uint4*)&Asm[r][cc * 8] = v;
      }
    } else {
      const bool valid = grow < nRows;
      const int g = valid ? batch[grow] : 0;
      const uint4 zero = {0u, 0u, 0u, 0u};
      int k = q * 80;
      const int kend = k + 80;
      while (k < kend) {
        if (k < 128) {
          uint4 v = valid ? *(const uint4*)(xb + (size_t)grow * 128 + k) : zero;
          *(uint4*)&Asm[r][k] = v; k += 8;
        } else if (k < 256) {
          float4 f = valid ? *(const float4*)(aggin + (size_t)grow * 128 + (k - 128))
                           : float4{0.f, 0.f, 0.f, 0.f};
          ushort4 o;
          o.x = f2bf(f.x); o.y = f2bf(f.y); o.z = f2bf(f.z); o.w = f2bf(f.w);
          *(ushort4*)&Asm[r][k] = o; k += 4;
        } else if (k < 288) {
          uint4 v = valid ? *(const uint4*)(ub + g * 32 + (k - 256)) : zero;
          *(uint4*)&Asm[r][k] = v; k += 8;
        } else {
          *(uint4*)&Asm[r][k] = zero; k += 8;
        }
      }
    }
  }

  const int w = tid >> 6;
  const int lane = tid & 63;
  const int l15 = lane & 15, lg = lane >> 4;

  f32x4 acc[8];
#pragma unroll
  for (int ni = 0; ni < 8; ++ni) acc[ni] = f32x4{0.f, 0.f, 0.f, 0.f};

  // ---- GEMM1: C1[128x128] = A[128x320] @ W1 ----
  for (int kc = 0; kc < 5; ++kc) {
    {
      const int n = tid >> 2, qq = tid & 3;
      const unsigned short* src = W1T + (size_t)n * 320 + kc * 64 + qq * 16;
      *(uint4*)&Bsm[n][qq * 16]     = *(const uint4*)src;
      *(uint4*)&Bsm[n][qq * 16 + 8] = *(const uint4*)(src + 8);
    }
    __syncthreads();
    bf16x8 a0 = *(bf16x8*)&Asm[w * 16 + l15][kc * 64 + lg * 8];
    bf16x8 a1 = *(bf16x8*)&Asm[w * 16 + l15][kc * 64 + 32 + lg * 8];
#pragma unroll
    for (int ni = 0; ni < 8; ++ni) {
      bf16x8 bb0 = *(bf16x8*)&Bsm[ni * 16 + l15][lg * 8];
      bf16x8 bb1 = *(bf16x8*)&Bsm[ni * 16 + l15][32 + lg * 8];
      acc[ni] = __builtin_amdgcn_mfma_f32_16x16x32_bf16(a0, bb0, acc[ni], 0, 0, 0);
      acc[ni] = __builtin_amdgcn_mfma_f32_16x16x32_bf16(a1, bb1, acc[ni], 0, 0, 0);
    }
    __syncthreads();
  }

  // ---- h1 = relu(C1 + b1) -> Hsm (bf16); wave writes only its own rows ----
#pragma unroll
  for (int ni = 0; ni < 8; ++ni) {
    const int ncol = l15 + ni * 16;
    const float bias = cb1[ncol];
#pragma unroll
    for (int reg = 0; reg < 4; ++reg) {
      const int mrow = w * 16 + lg * 4 + reg;
      Hsm[mrow][ncol] = f2bf(fmaxf(acc[ni][reg] + bias, 0.f));
    }
  }

  // ---- GEMM2: C2 = H1[128x128] @ W2 ----
  f32x4 acc2[8];
#pragma unroll
  for (int ni = 0; ni < 8; ++ni) acc2[ni] = f32x4{0.f, 0.f, 0.f, 0.f};
  for (int kc = 0; kc < 2; ++kc) {
    {
      const int n = tid >> 2, qq = tid & 3;
      const unsigned short* src = W2T + (size_t)n * 128 + kc * 64 + qq * 16;
      *(uint4*)&Bsm[n][qq * 16]     = *(const uint4*)src;
      *(uint4*)&Bsm[n][qq * 16 + 8] = *(const uint4*)(src + 8);
    }
    __syncthreads();  // covers Hsm writes + Bsm restage
    bf16x8 a0 = *(bf16x8*)&Hsm[w * 16 + l15][kc * 64 + lg * 8];
    bf16x8 a1 = *(bf16x8*)&Hsm[w * 16 + l15][kc * 64 + 32 + lg * 8];
#pragma unroll
    for (int ni = 0; ni < 8; ++ni) {
      bf16x8 bb0 = *(bf16x8*)&Bsm[ni * 16 + l15][lg * 8];
      bf16x8 bb1 = *(bf16x8*)&Bsm[ni * 16 + l15][32 + lg * 8];
      acc2[ni] = __builtin_amdgcn_mfma_f32_16x16x32_bf16(a0, bb0, acc2[ni], 0, 0, 0);
      acc2[ni] = __builtin_amdgcn_mfma_f32_16x16x32_bf16(a1, bb1, acc2[ni], 0, 0, 0);
    }
    __syncthreads();
  }

  // ---- epilogue: bias + relu + LayerNorm + store (+ scatter for edges) ----
  float hv[8][4];
  float sreg[4] = {0.f, 0.f, 0.f, 0.f}, ssreg[4] = {0.f, 0.f, 0.f, 0.f};
#pragma unroll
  for (int ni = 0; ni < 8; ++ni) {
    const int ncol = l15 + ni * 16;
    const float bias = cb2[ncol];
#pragma unroll
    for (int reg = 0; reg < 4; ++reg) {
      const float h = fmaxf(acc2[ni][reg] + bias, 0.f);
      hv[ni][reg] = h;
      sreg[reg] += h; ssreg[reg] += h * h;
    }
  }
#pragma unroll
  for (int reg = 0; reg < 4; ++reg) {
    float s = sreg[reg], ss = ssreg[reg];
#pragma unroll
    for (int off = 1; off < 16; off <<= 1) {
      s += __shfl_xor(s, off, 64);
      ss += __shfl_xor(ss, off, 64);
    }
    sreg[reg] = s; ssreg[reg] = ss;
  }
#pragma unroll
  for (int reg = 0; reg < 4; ++reg) {
    const int mrow = w * 16 + lg * 4 + reg;
    const int grow = blockIdx.x * 128 + mrow;
    if (MODE == 1 && grow >= nRows) continue;
    const float mu = sreg[reg] * (1.f / 128.f);
    const float var = ssreg[reg] * (1.f / 128.f) - mu * mu;
    const float rstd = rsqrtf(var + EPSV);
    int rcv = 0;
    if (MODE == 0) rcv = colIdx[grow];
#pragma unroll
    for (int ni = 0; ni < 8; ++ni) {
      const int ncol = l15 + ni * 16;
      const float y = cg[ncol] * (hv[ni][reg] - mu) * rstd + cbt[ncol];
      out[(size_t)grow * 128 + ncol] = y;
      if (MODE == 0) atomicAdd(&aggout[(size_t)rcv * 128 + ncol], y);
    }
  }
}

// ---------------- segment-sum to globals (two-level) ----------------
__global__ __launch_bounds__(256) void seg_partial(
    const float* __restrict__ data, const int* __restrict__ rowIdx,
    const int* __restrict__ batch, int n, int chunk,
    float* __restrict__ outbins) {
  __shared__ float bins[NG][128];
  const int t = threadIdx.x;
  for (int i = t; i < NG * 128; i += 256) ((float*)bins)[i] = 0.f;
  __syncthreads();
  const int start = blockIdx.x * chunk;
  const int end = min(n, start + chunk);
  const int ch = t & 127, sub = t >> 7;
  for (int pos = start + sub; pos < end; pos += 2) {
    const int g = rowIdx ? batch[rowIdx[pos]] : batch[pos];
    atomicAdd(&bins[g][ch], data[(size_t)pos * 128 + ch]);
  }
  __syncthreads();
  for (int i = t; i < NG * 128; i += 256)
    atomicAdd(&outbins[i], ((float*)bins)[i]);
}

// ---------------- global MLP (tiny) ----------------
__global__ __launch_bounds__(128) void glob_kernel(
    const float* __restrict__ u, const float* __restrict__ n2g,
    const float* __restrict__ e2g,
    const float* __restrict__ gW1, const float* __restrict__ gb1,
    const float* __restrict__ gW2, const float* __restrict__ gb2,
    const float* __restrict__ gg, const float* __restrict__ gbt,
    float* __restrict__ outU) {
  __shared__ float in[288];
  __shared__ float h1[128];
  __shared__ float red[4];
  const int g = blockIdx.x, t = threadIdx.x;
  if (t < 32) in[t] = u[g * 32 + t];
  in[32 + t] = n2g[g * 128 + t];
  in[160 + t] = e2g[g * 128 + t];
  __syncthreads();
  float a = gb1[t];
  for (int k = 0; k < 288; ++k) a += in[k] * gW1[k * 128 + t];
  h1[t] = fmaxf(a, 0.f);
  __syncthreads();
  float h = gb2[t];
  for (int k = 0; k < 128; ++k) h += h1[k] * gW2[k * 128 + t];
  h = fmaxf(h, 0.f);
  float s = h, ss = h * h;
  for (int off = 1; off < 64; off <<= 1) {
    s += __shfl_xor(s, off, 64);
    ss += __shfl_xor(ss, off, 64);
  }
  if ((t & 63) == 0) { red[(t >> 6) * 2] = s; red[(t >> 6) * 2 + 1] = ss; }
  __syncthreads();
  const float S = red[0] + red[2], SS = red[1] + red[3];
  const float mu = S * (1.f / 128.f);
  const float var = SS * (1.f / 128.f) - mu * mu;
  const float rstd = rsqrtf(var + EPSV);
  outU[g * 128 + t] = gg[t] * (h - mu) * rstd + gbt[t];
}

// ---------------- launch ----------------
extern "C" void kernel_launch(void* const* d_in, const int* in_sizes, int n_in,
                              void* d_out, int out_size, void* d_ws,
                              size_t ws_size, hipStream_t stream) {
  const float* x   = (const float*)d_in[0];
  const float* e   = (const float*)d_in[1];
  const float* u   = (const float*)d_in[2];
  const int* eidx  = (const int*)d_in[3];
  const int* batch = (const int*)d_in[4];
  const float* eW1 = (const float*)d_in[5];
  const float* eb1 = (const float*)d_in[6];
  const float* eW2 = (const float*)d_in[7];
  const float* eb2 = (const float*)d_in[8];
  const float* eg  = (const float*)d_in[9];
  const float* ebt = (const float*)d_in[10];
  const float* nW1 = (const float*)d_in[11];
  const float* nb1 = (const float*)d_in[12];
  const float* nW2 = (const float*)d_in[13];
  const float* nb2 = (const float*)d_in[14];
  const float* ng  = (const float*)d_in[15];
  const float* nbt = (const float*)d_in[16];
  const float* gW1 = (const float*)d_in[17];
  const float* gb1 = (const float*)d_in[18];
  const float* gW2 = (const float*)d_in[19];
  const float* gb2 = (const float*)d_in[20];
  const float* gg  = (const float*)d_in[21];
  const float* gbt = (const float*)d_in[22];

  char* ws = (char*)d_ws;
  float* e2n = (float*)(ws + 0);                       // 25,600,000 B
  float* e2g = (float*)(ws + 25600000);                // 32,768 B
  float* n2g = (float*)(ws + 25632768);                // 32,768 B
  unsigned short* xb   = (unsigned short*)(ws + 25665536);  // 12,800,000 B
  unsigned short* eb   = (unsigned short*)(ws + 38465536);  // 51,200,000 B
  unsigned short* ub   = (unsigned short*)(ws + 89665536);  // 4,096 B
  unsigned short* eW1T = (unsigned short*)(ws + 89669632);  // 81,920 B
  unsigned short* eW2T = (unsigned short*)(ws + 89751552);  // 32,768 B
  unsigned short* nW1T = (unsigned short*)(ws + 89784320);  // 81,920 B
  unsigned short* nW2T = (unsigned short*)(ws + 89866240);  // 32,768 B

  // zero the accumulators (e2n + e2g + n2g are contiguous)
  hipMemsetAsync(ws, 0, 25665536, stream);

  cvt_vec_kernel<<<2048, 256, 0, stream>>>(x, e, xb, eb);
  cvt_small_kernel<<<456, 256, 0, stream>>>(u, eW1, eW2, nW1, nW2, ub, eW1T,
                                            eW2T, nW1T, nW2T);

  float* outX = (float*)d_out;                 // [50000][128]
  float* outE = outX + (size_t)NN * 128;       // [800000][128]
  float* outU = outE + (size_t)NE * 128;       // [64][128]

  const int* rowI = eidx;        // edge_index[0] (sender)
  const int* colI = eidx + NE;   // edge_index[1] (receiver)

  mlp_kernel<0><<<NE / 128, 512, 0, stream>>>(
      eb, xb, ub, nullptr, rowI, colI, batch, eW1T, eW2T, eb1, eb2, eg, ebt,
      outE, e2n, NE);
  seg_partial<<<256, 256, 0, stream>>>(outE, rowI, batch, NE, NE / 256, e2g);
  mlp_kernel<1><<<(NN + 127) / 128, 512, 0, stream>>>(
      nullptr, xb, ub, e2n, nullptr, nullptr, batch, nW1T, nW2T, nb1, nb2, ng,
      nbt, outX, nullptr, NN);
  seg_partial<<<256, 256, 0, stream>>>(outX, nullptr, batch, NN,
                                       (NN + 255) / 256, n2g);
  glob_kernel<<<NG, 128, 0, stream>>>(u, n2g, e2g, gW1, gb1, gW2, gb2, gg, gbt,
                                      outU);
}

// Round 2
// 1206.338 us; speedup vs baseline: 1.5767x; 1.5767x over previous
//
#include <hip/hip_runtime.h>
#include <hip/hip_bf16.h>

typedef __attribute__((ext_vector_type(8))) short bf16x8;
typedef __attribute__((ext_vector_type(4))) float f32x4;

#define EPSV 1e-5f

#define NN 50000
#define NE 800000
#define NG 64

__device__ __forceinline__ unsigned short f2bf(float f) {
  union { float f; unsigned u; } v; v.f = f;
  unsigned r = v.u + 0x7FFFu + ((v.u >> 16) & 1u);
  return (unsigned short)(r >> 16);
}

// ---------------- conversion kernels ----------------

// x [50000*128] and e [800000*32] f32 -> bf16, vectorized
__global__ __launch_bounds__(256) void cvt_vec_kernel(
    const float* __restrict__ x, const float* __restrict__ e,
    unsigned short* __restrict__ xb, unsigned short* __restrict__ eb) {
  const int NX4 = (NN * 128) / 4;     // 1,600,000
  const int NE4 = (NE * 32) / 4;      // 6,400,000
  const int total = NX4 + NE4;
  for (int idx = blockIdx.x * 256 + threadIdx.x; idx < total;
       idx += gridDim.x * 256) {
    float4 v = (idx < NX4) ? ((const float4*)x)[idx]
                           : ((const float4*)e)[idx - NX4];
    ushort4 o;
    o.x = f2bf(v.x); o.y = f2bf(v.y); o.z = f2bf(v.z); o.w = f2bf(v.w);
    if (idx < NX4) ((ushort4*)xb)[idx] = o;
    else           ((ushort4*)eb)[idx - NX4] = o;
  }
}

// u + weight transposes (tiny)
__global__ __launch_bounds__(256) void cvt_small_kernel(
    const float* __restrict__ u,
    const float* __restrict__ eW1, const float* __restrict__ eW2,
    const float* __restrict__ nW1, const float* __restrict__ nW2,
    unsigned short* __restrict__ ub,
    unsigned short* __restrict__ eW1T, unsigned short* __restrict__ eW2T,
    unsigned short* __restrict__ nW1T, unsigned short* __restrict__ nW2T) {
  int i = blockIdx.x * 256 + threadIdx.x;
  const int R0 = NG * 32;          // 2048 : ub
  const int R1 = R0 + 128 * 320;   // eW1T  (K=320)
  const int R2 = R1 + 128 * 128;   // eW2T
  const int R3 = R2 + 128 * 320;   // nW1T  (K padded 288->320)
  const int R4 = R3 + 128 * 128;   // nW2T
  if (i < R0) {
    ub[i] = f2bf(u[i]);
  } else if (i < R1) {
    int j = i - R0; int n = j / 320, k = j % 320;
    eW1T[j] = f2bf(eW1[k * 128 + n]);
  } else if (i < R2) {
    int j = i - R1; int n = j / 128, k = j % 128;
    eW2T[j] = f2bf(eW2[k * 128 + n]);
  } else if (i < R3) {
    int j = i - R2; int n = j / 320, k = j % 320;
    nW1T[j] = (k < 288) ? f2bf(nW1[k * 128 + n]) : (unsigned short)0;
  } else if (i < R4) {
    int j = i - R3; int n = j / 128, k = j % 128;
    nW2T[j] = f2bf(nW2[k * 128 + n]);
  }
}

// edge gid: eg[i] = batch[row[i]] (removes dependent-load chain in reduction)
__global__ __launch_bounds__(256) void edge_gid_kernel(
    const int* __restrict__ rowIdx, const int* __restrict__ batch,
    int* __restrict__ eg) {
  int i = blockIdx.x * 256 + threadIdx.x;
  if (i < NE) eg[i] = batch[rowIdx[i]];
}

// ---------------- fused MLP kernel (edge MODE=0 / node MODE=1) ----------------
// 128 rows per block, 512 threads = 8 waves; wave w owns rows w*16..w*16+15
// (all 128 output cols), so LayerNorm reduces purely via shfl within the wave.
// MODE 1 additionally reduces its rows into n2g (batch sorted -> tiny g-range).
template <int MODE>
__global__ __launch_bounds__(512, 1) void mlp_kernel(
    const unsigned short* __restrict__ ebuf,  // MODE0: eb [NE][32]
    const unsigned short* __restrict__ xb,    // [NN][128]
    const unsigned short* __restrict__ ub,    // [NG][32]
    const float* __restrict__ aggin,          // MODE1: e2n [NN][128] f32
    const int* __restrict__ rowIdx, const int* __restrict__ colIdx,
    const int* __restrict__ batch,
    const unsigned short* __restrict__ W1T,   // [128][320] bf16
    const unsigned short* __restrict__ W2T,   // [128][128] bf16
    const float* __restrict__ b1, const float* __restrict__ b2,
    const float* __restrict__ gam, const float* __restrict__ bet,
    float* __restrict__ out, float* __restrict__ aggout, int nRows) {
  __shared__ unsigned short Asm[128][328];  // A tile, K padded to 320 (+8 pad)
  __shared__ unsigned short Bsm[128][72];   // weight K-chunk [N][64] (+8 pad)
  __shared__ unsigned short Hsm[128][136];  // h1 bf16 [M][128] (+8 pad)
  __shared__ float cb1[128], cb2[128], cg[128], cbt[128];

  const int tid = threadIdx.x;
  if (tid < 128) {
    cb1[tid] = b1[tid]; cb2[tid] = b2[tid];
    cg[tid] = gam[tid]; cbt[tid] = bet[tid];
  }

  // ---- stage A tile: 4 threads per row ----
  {
    const int r = tid >> 2, q = tid & 3;
    const int grow = blockIdx.x * 128 + r;
    if (MODE == 0) {
      const int rcv = colIdx[grow];
      const int snd = rowIdx[grow];
      const int g = batch[snd];
      const uint4* esrc = (const uint4*)(ebuf + (size_t)grow * 32);
      const uint4* xr = (const uint4*)(xb + (size_t)rcv * 128);
      const uint4* xs = (const uint4*)(xb + (size_t)snd * 128);
      const uint4* us = (const uint4*)(ub + g * 32);
#pragma unroll
      for (int c = 0; c < 10; ++c) {
        const int cc = q * 10 + c;
        uint4 v;
        if (cc < 4)       v = esrc[cc];
        else if (cc < 20) v = xr[cc - 4];
        else if (cc < 36) v = xs[cc - 20];
        else              v = us[cc - 36];
        *(uint4*)&Asm[r][cc * 8] = v;
      }
    } else {
      const bool valid = grow < nRows;
      const int g = valid ? batch[grow] : 0;
      const uint4 zero = {0u, 0u, 0u, 0u};
      int k = q * 80;
      const int kend = k + 80;
      while (k < kend) {
        if (k < 128) {
          uint4 v = valid ? *(const uint4*)(xb + (size_t)grow * 128 + k) : zero;
          *(uint4*)&Asm[r][k] = v; k += 8;
        } else if (k < 256) {
          float4 f = valid ? *(const float4*)(aggin + (size_t)grow * 128 + (k - 128))
                           : float4{0.f, 0.f, 0.f, 0.f};
          ushort4 o;
          o.x = f2bf(f.x); o.y = f2bf(f.y); o.z = f2bf(f.z); o.w = f2bf(f.w);
          *(ushort4*)&Asm[r][k] = o; k += 4;
        } else if (k < 288) {
          uint4 v = valid ? *(const uint4*)(ub + g * 32 + (k - 256)) : zero;
          *(uint4*)&Asm[r][k] = v; k += 8;
        } else {
          *(uint4*)&Asm[r][k] = zero; k += 8;
        }
      }
    }
  }

  const int w = tid >> 6;
  const int lane = tid & 63;
  const int l15 = lane & 15, lg = lane >> 4;

  f32x4 acc[8];
#pragma unroll
  for (int ni = 0; ni < 8; ++ni) acc[ni] = f32x4{0.f, 0.f, 0.f, 0.f};

  // ---- GEMM1: C1[128x128] = A[128x320] @ W1 ----
  for (int kc = 0; kc < 5; ++kc) {
    {
      const int n = tid >> 2, qq = tid & 3;
      const unsigned short* src = W1T + (size_t)n * 320 + kc * 64 + qq * 16;
      *(uint4*)&Bsm[n][qq * 16]     = *(const uint4*)src;
      *(uint4*)&Bsm[n][qq * 16 + 8] = *(const uint4*)(src + 8);
    }
    __syncthreads();
    bf16x8 a0 = *(bf16x8*)&Asm[w * 16 + l15][kc * 64 + lg * 8];
    bf16x8 a1 = *(bf16x8*)&Asm[w * 16 + l15][kc * 64 + 32 + lg * 8];
#pragma unroll
    for (int ni = 0; ni < 8; ++ni) {
      bf16x8 bb0 = *(bf16x8*)&Bsm[ni * 16 + l15][lg * 8];
      bf16x8 bb1 = *(bf16x8*)&Bsm[ni * 16 + l15][32 + lg * 8];
      acc[ni] = __builtin_amdgcn_mfma_f32_16x16x32_bf16(a0, bb0, acc[ni], 0, 0, 0);
      acc[ni] = __builtin_amdgcn_mfma_f32_16x16x32_bf16(a1, bb1, acc[ni], 0, 0, 0);
    }
    __syncthreads();
  }

  // ---- h1 = relu(C1 + b1) -> Hsm (bf16); wave writes only its own rows ----
#pragma unroll
  for (int ni = 0; ni < 8; ++ni) {
    const int ncol = l15 + ni * 16;
    const float bias = cb1[ncol];
#pragma unroll
    for (int reg = 0; reg < 4; ++reg) {
      const int mrow = w * 16 + lg * 4 + reg;
      Hsm[mrow][ncol] = f2bf(fmaxf(acc[ni][reg] + bias, 0.f));
    }
  }

  // ---- GEMM2: C2 = H1[128x128] @ W2 ----
  f32x4 acc2[8];
#pragma unroll
  for (int ni = 0; ni < 8; ++ni) acc2[ni] = f32x4{0.f, 0.f, 0.f, 0.f};
  for (int kc = 0; kc < 2; ++kc) {
    {
      const int n = tid >> 2, qq = tid & 3;
      const unsigned short* src = W2T + (size_t)n * 128 + kc * 64 + qq * 16;
      *(uint4*)&Bsm[n][qq * 16]     = *(const uint4*)src;
      *(uint4*)&Bsm[n][qq * 16 + 8] = *(const uint4*)(src + 8);
    }
    __syncthreads();  // covers Hsm writes + Bsm restage
    bf16x8 a0 = *(bf16x8*)&Hsm[w * 16 + l15][kc * 64 + lg * 8];
    bf16x8 a1 = *(bf16x8*)&Hsm[w * 16 + l15][kc * 64 + 32 + lg * 8];
#pragma unroll
    for (int ni = 0; ni < 8; ++ni) {
      bf16x8 bb0 = *(bf16x8*)&Bsm[ni * 16 + l15][lg * 8];
      bf16x8 bb1 = *(bf16x8*)&Bsm[ni * 16 + l15][32 + lg * 8];
      acc2[ni] = __builtin_amdgcn_mfma_f32_16x16x32_bf16(a0, bb0, acc2[ni], 0, 0, 0);
      acc2[ni] = __builtin_amdgcn_mfma_f32_16x16x32_bf16(a1, bb1, acc2[ni], 0, 0, 0);
    }
    __syncthreads();
  }

  // MODE 1: alias n2g bins over Asm (A tile dead after GEMM1)
  float* bins = (float*)&Asm[0][0];  // 64*128 f32 = 32 KB (Asm is 84 KB)
  if (MODE == 1) {
    for (int i = tid; i < NG * 128; i += 512) bins[i] = 0.f;
  }

  // ---- epilogue: bias + relu + LayerNorm + store (+ scatter) ----
  float hv[8][4];
  float sreg[4] = {0.f, 0.f, 0.f, 0.f}, ssreg[4] = {0.f, 0.f, 0.f, 0.f};
#pragma unroll
  for (int ni = 0; ni < 8; ++ni) {
    const int ncol = l15 + ni * 16;
    const float bias = cb2[ncol];
#pragma unroll
    for (int reg = 0; reg < 4; ++reg) {
      const float h = fmaxf(acc2[ni][reg] + bias, 0.f);
      hv[ni][reg] = h;
      sreg[reg] += h; ssreg[reg] += h * h;
    }
  }
#pragma unroll
  for (int reg = 0; reg < 4; ++reg) {
    float s = sreg[reg], ss = ssreg[reg];
#pragma unroll
    for (int off = 1; off < 16; off <<= 1) {
      s += __shfl_xor(s, off, 64);
      ss += __shfl_xor(ss, off, 64);
    }
    sreg[reg] = s; ssreg[reg] = ss;
  }
  if (MODE == 1) __syncthreads();  // bins zeroed before any atomic lands
#pragma unroll
  for (int reg = 0; reg < 4; ++reg) {
    const int mrow = w * 16 + lg * 4 + reg;
    const int grow = blockIdx.x * 128 + mrow;
    if (MODE == 1 && grow >= nRows) continue;
    const float mu = sreg[reg] * (1.f / 128.f);
    const float var = ssreg[reg] * (1.f / 128.f) - mu * mu;
    const float rstd = rsqrtf(var + EPSV);
    int rcv = 0, g = 0;
    if (MODE == 0) rcv = colIdx[grow];
    else           g = batch[grow];
#pragma unroll
    for (int ni = 0; ni < 8; ++ni) {
      const int ncol = l15 + ni * 16;
      const float y = cg[ncol] * (hv[ni][reg] - mu) * rstd + cbt[ncol];
      out[(size_t)grow * 128 + ncol] = y;
      if (MODE == 0) atomicAdd(&aggout[(size_t)rcv * 128 + ncol], y);
      else           atomicAdd(&bins[g * 128 + ncol], y);
    }
  }
  // MODE 1: flush block bins into n2g (batch sorted -> tiny [gmin,gmax] range)
  if (MODE == 1) {
    __syncthreads();
    const int first = blockIdx.x * 128;
    const int last = min(first + 127, nRows - 1);
    const int gmin = batch[first], gmax = batch[last];
    const int cnt = (gmax - gmin + 1) * 128;
    for (int i = tid; i < cnt; i += 512)
      atomicAdd(&aggout[gmin * 128 + i], bins[gmin * 128 + i]);
  }
}

// ---------------- edge->global segment sum: LDS bins -> per-block partials ----
__global__ __launch_bounds__(512) void seg_e2g_kernel(
    const float* __restrict__ data, const int* __restrict__ gid,
    float* __restrict__ part) {
  __shared__ float bins[NG * 128];
  const int t = threadIdx.x;
  for (int i = t; i < NG * 128; i += 512) bins[i] = 0.f;
  __syncthreads();
  const int chunk = NE / 256;  // 3125
  const int start = blockIdx.x * chunk;
  const int end = start + chunk;
  const int c4 = (t & 31) * 4, sub = t >> 5;  // 16 subs of 32 threads
  for (int pos = start + sub; pos < end; pos += 16) {
    const int g = gid[pos];
    const float4 v = *(const float4*)(data + (size_t)pos * 128 + c4);
    float* b = &bins[g * 128 + c4];
    atomicAdd(b, v.x);
    atomicAdd(b + 1, v.y);
    atomicAdd(b + 2, v.z);
    atomicAdd(b + 3, v.w);
  }
  __syncthreads();
  float* dst = part + (size_t)blockIdx.x * (NG * 128);
  for (int i = t; i < NG * 128; i += 512) dst[i] = bins[i];
}

// sum the 256 partials -> e2g (non-atomic)
__global__ __launch_bounds__(256) void e2g_reduce_kernel(
    const float* __restrict__ part, float* __restrict__ e2g) {
  const int i = blockIdx.x * 256 + threadIdx.x;  // 8192 total
  float s = 0.f;
#pragma unroll 8
  for (int p = 0; p < 256; ++p) s += part[(size_t)p * (NG * 128) + i];
  e2g[i] = s;
}

// ---------------- global MLP (tiny) ----------------
__global__ __launch_bounds__(128) void glob_kernel(
    const float* __restrict__ u, const float* __restrict__ n2g,
    const float* __restrict__ e2g,
    const float* __restrict__ gW1, const float* __restrict__ gb1,
    const float* __restrict__ gW2, const float* __restrict__ gb2,
    const float* __restrict__ gg, const float* __restrict__ gbt,
    float* __restrict__ outU) {
  __shared__ float in[288];
  __shared__ float h1[128];
  __shared__ float red[4];
  const int g = blockIdx.x, t = threadIdx.x;
  if (t < 32) in[t] = u[g * 32 + t];
  in[32 + t] = n2g[g * 128 + t];
  in[160 + t] = e2g[g * 128 + t];
  __syncthreads();
  float a = gb1[t];
  for (int k = 0; k < 288; ++k) a += in[k] * gW1[k * 128 + t];
  h1[t] = fmaxf(a, 0.f);
  __syncthreads();
  float h = gb2[t];
  for (int k = 0; k < 128; ++k) h += h1[k] * gW2[k * 128 + t];
  h = fmaxf(h, 0.f);
  float s = h, ss = h * h;
  for (int off = 1; off < 64; off <<= 1) {
    s += __shfl_xor(s, off, 64);
    ss += __shfl_xor(ss, off, 64);
  }
  if ((t & 63) == 0) { red[(t >> 6) * 2] = s; red[(t >> 6) * 2 + 1] = ss; }
  __syncthreads();
  const float S = red[0] + red[2], SS = red[1] + red[3];
  const float mu = S * (1.f / 128.f);
  const float var = SS * (1.f / 128.f) - mu * mu;
  const float rstd = rsqrtf(var + EPSV);
  outU[g * 128 + t] = gg[t] * (h - mu) * rstd + gbt[t];
}

// ---------------- launch ----------------
extern "C" void kernel_launch(void* const* d_in, const int* in_sizes, int n_in,
                              void* d_out, int out_size, void* d_ws,
                              size_t ws_size, hipStream_t stream) {
  const float* x   = (const float*)d_in[0];
  const float* e   = (const float*)d_in[1];
  const float* u   = (const float*)d_in[2];
  const int* eidx  = (const int*)d_in[3];
  const int* batch = (const int*)d_in[4];
  const float* eW1 = (const float*)d_in[5];
  const float* eb1 = (const float*)d_in[6];
  const float* eW2 = (const float*)d_in[7];
  const float* eb2 = (const float*)d_in[8];
  const float* eg  = (const float*)d_in[9];
  const float* ebt = (const float*)d_in[10];
  const float* nW1 = (const float*)d_in[11];
  const float* nb1 = (const float*)d_in[12];
  const float* nW2 = (const float*)d_in[13];
  const float* nb2 = (const float*)d_in[14];
  const float* ng  = (const float*)d_in[15];
  const float* nbt = (const float*)d_in[16];
  const float* gW1 = (const float*)d_in[17];
  const float* gb1 = (const float*)d_in[18];
  const float* gW2 = (const float*)d_in[19];
  const float* gb2 = (const float*)d_in[20];
  const float* gg  = (const float*)d_in[21];
  const float* gbt = (const float*)d_in[22];

  char* ws = (char*)d_ws;
  float* e2n = (float*)(ws + 0);                       // 25,600,000 B
  float* e2g = (float*)(ws + 25600000);                // 32,768 B
  float* n2g = (float*)(ws + 25632768);                // 32,768 B
  unsigned short* xb   = (unsigned short*)(ws + 25665536);  // 12,800,000 B
  unsigned short* eb   = (unsigned short*)(ws + 38465536);  // 51,200,000 B
  unsigned short* ub   = (unsigned short*)(ws + 89665536);  // 4,096 B
  unsigned short* eW1T = (unsigned short*)(ws + 89669632);  // 81,920 B
  unsigned short* eW2T = (unsigned short*)(ws + 89751552);  // 32,768 B
  unsigned short* nW1T = (unsigned short*)(ws + 89784320);  // 81,920 B
  unsigned short* nW2T = (unsigned short*)(ws + 89866240);  // 32,768 B
  int* eg_arr          = (int*)(ws + 89899008);             // 3,200,000 B
  float* e2g_part      = (float*)(ws + 93099008);           // 8,388,608 B
  // total ws use: ~101.5 MB

  // zero the accumulators (e2n + e2g + n2g are contiguous)
  hipMemsetAsync(ws, 0, 25665536, stream);

  cvt_vec_kernel<<<2048, 256, 0, stream>>>(x, e, xb, eb);
  cvt_small_kernel<<<456, 256, 0, stream>>>(u, eW1, eW2, nW1, nW2, ub, eW1T,
                                            eW2T, nW1T, nW2T);

  float* outX = (float*)d_out;                 // [50000][128]
  float* outE = outX + (size_t)NN * 128;       // [800000][128]
  float* outU = outE + (size_t)NE * 128;       // [64][128]

  const int* rowI = eidx;        // edge_index[0] (sender)
  const int* colI = eidx + NE;   // edge_index[1] (receiver)

  edge_gid_kernel<<<(NE + 255) / 256, 256, 0, stream>>>(rowI, batch, eg_arr);

  mlp_kernel<0><<<NE / 128, 512, 0, stream>>>(
      eb, xb, ub, nullptr, rowI, colI, batch, eW1T, eW2T, eb1, eb2, eg, ebt,
      outE, e2n, NE);
  seg_e2g_kernel<<<256, 512, 0, stream>>>(outE, eg_arr, e2g_part);
  e2g_reduce_kernel<<<32, 256, 0, stream>>>(e2g_part, e2g);
  mlp_kernel<1><<<(NN + 127) / 128, 512, 0, stream>>>(
      nullptr, xb, ub, e2n, nullptr, nullptr, batch, nW1T, nW2T, nb1, nb2, ng,
      nbt, outX, n2g, NN);
  glob_kernel<<<NG, 128, 0, stream>>>(u, n2g, e2g, gW1, gb1, gW2, gb2, gg, gbt,
                                      outU);
}